// Round 1
// baseline (315905.176 us; speedup 1.0000x reference)
//
#include <hip/hip_runtime.h>

#define T_STEPS  8192
#define INPUT_N  256
#define OUTPUT_N 256
#define RES_N    4096
#define NB       256   // blocks (1 per CU)
#define NT       512   // threads per block (8 waves)
#define RPB      16    // W_res rows per block
#define NRG      4     // rows per thread (rowgroup size)
#define NCG      128   // col-group count (threads per rowgroup)
#define CPT      32    // state cols per thread, strided by NCG

// Persistent ESN kernel. Each block owns 16 rows of W_res (in VGPRs),
// one row of W_out, 16 rows of W_in. Per timestep: grid barrier via
// agent-scope flags, stage state into LDS, compute pred_{t-1} and state_t.
__global__ __launch_bounds__(NT, 2) void esn_persistent(
    const float* __restrict__ X,       // [T, 256]
    const float* __restrict__ state0,  // [4096]
    const float* __restrict__ W_in,    // [4096, 256]
    const float* __restrict__ W_res,   // [4096, 4096]
    const float* __restrict__ W_out,   // [256, 4096]
    float* __restrict__ out,           // [T, 256]
    float* __restrict__ stbuf,         // ws: [2][4096]
    int*   __restrict__ flags)         // ws: [2][256], zeroed per call
{
    const int tid  = threadIdx.x;
    const int bid  = blockIdx.x;
    const int wid  = tid >> 6;          // wave 0..7
    const int lane = tid & 63;
    const int rg   = tid >> 7;          // rowgroup 0..3 (rows rg*4..rg*4+3)
    const int cg   = tid & (NCG - 1);   // colgroup 0..127

    __shared__ float lds_s[RES_N];      // staged state_{t-1}
    __shared__ float lds_x[INPUT_N];    // staged x_t
    __shared__ float lds_part[8][4];    // per-wave row partials
    __shared__ float lds_pp[8];         // per-wave pred partials

    // ---- one-time: load persistent weights into registers ----
    // W_res rows bid*16 + rg*4 + r, cols cg + 128*c  (coalesced: lane dim = cg)
    float wres[NRG][CPT];
    float win[NRG][2];
    float wout[8];
#pragma unroll
    for (int r = 0; r < NRG; ++r) {
        const int grow = bid * RPB + rg * NRG + r;
        const float* wr = W_res + (size_t)grow * RES_N;
#pragma unroll
        for (int c = 0; c < CPT; ++c) wres[r][c] = wr[cg + NCG * c];
        const float* wi = W_in + (size_t)grow * INPUT_N;
        win[r][0] = wi[cg];
        win[r][1] = wi[cg + NCG];
    }
    {
        const float* wo = W_out + (size_t)bid * RES_N;
#pragma unroll
        for (int c = 0; c < 8; ++c) wout[c] = wo[tid + NT * c];
    }

    // Iteration t: stage state_{t-1}; compute pred_{t-1} (t>0) and state_t (t<T).
    for (int t = 0; t <= T_STEPS; ++t) {
        const int par  = t & 1;
        const int ppar = (t - 1) & 1;  // only used when t > 0

        // ---- grid barrier: wait until every block published state_{t-1} ----
        if (t > 0) {
            if (tid < NB) {
                const int* f = flags + ppar * NB + tid;
                while (__hip_atomic_load(f, __ATOMIC_RELAXED,
                                         __HIP_MEMORY_SCOPE_AGENT) < t) { }
            }
            __threadfence();  // acquire: order subsequent state loads
        }
        __syncthreads();

        // ---- stage state_{t-1} into LDS (and keep own slice in regs) ----
        const float* src = (t == 0) ? state0 : (stbuf + (size_t)ppar * RES_N);
        float sv[8];
#pragma unroll
        for (int c = 0; c < 8; ++c) {
            sv[c] = __hip_atomic_load(src + tid + NT * c, __ATOMIC_RELAXED,
                                      __HIP_MEMORY_SCOPE_AGENT);
            lds_s[tid + NT * c] = sv[c];
        }
        if (t < T_STEPS && tid < INPUT_N)
            lds_x[tid] = X[(size_t)t * INPUT_N + tid];
        __syncthreads();

        // ---- pred_{t-1} = W_out[bid] . state_{t-1} (reuses staged regs) ----
        if (t > 0) {
            float pp = 0.f;
#pragma unroll
            for (int c = 0; c < 8; ++c) pp += wout[c] * sv[c];
#pragma unroll
            for (int m = 32; m > 0; m >>= 1) pp += __shfl_xor(pp, m, 64);
            if (lane == 0) lds_pp[wid] = pp;
        }

        // ---- state_t partials: 4 rows x 32 strided cols per thread ----
        if (t < T_STEPS) {
            float p0 = 0.f, p1 = 0.f, p2 = 0.f, p3 = 0.f;
#pragma unroll
            for (int c = 0; c < CPT; ++c) {
                const float s = lds_s[cg + NCG * c];  // bank = cg%32: conflict-free
                p0 += wres[0][c] * s;
                p1 += wres[1][c] * s;
                p2 += wres[2][c] * s;
                p3 += wres[3][c] * s;
            }
            const float x0 = lds_x[cg];
            const float x1 = lds_x[cg + NCG];
            p0 += win[0][0] * x0 + win[0][1] * x1;
            p1 += win[1][0] * x0 + win[1][1] * x1;
            p2 += win[2][0] * x0 + win[2][1] * x1;
            p3 += win[3][0] * x0 + win[3][1] * x1;
#pragma unroll
            for (int m = 32; m > 0; m >>= 1) {
                p0 += __shfl_xor(p0, m, 64);
                p1 += __shfl_xor(p1, m, 64);
                p2 += __shfl_xor(p2, m, 64);
                p3 += __shfl_xor(p3, m, 64);
            }
            if (lane == 0) {
                lds_part[wid][0] = p0;
                lds_part[wid][1] = p1;
                lds_part[wid][2] = p2;
                lds_part[wid][3] = p3;
            }
        }
        __syncthreads();

        // ---- finals: write pred, apply tanh, publish state slice + flag ----
        if (t > 0 && tid == 0) {
            float pr = 0.f;
#pragma unroll
            for (int w = 0; w < 8; ++w) pr += lds_pp[w];
            out[(size_t)(t - 1) * OUTPUT_N + bid] = pr;
        }
        if (t < T_STEPS) {
            if (tid < RPB) {
                const int w0 = (tid >> 2) * 2;  // two waves of this rowgroup
                const float v = lds_part[w0][tid & 3] + lds_part[w0 + 1][tid & 3];
                const float ns = tanhf(v);
                __hip_atomic_store(stbuf + (size_t)par * RES_N + bid * RPB + tid,
                                   ns, __ATOMIC_RELAXED, __HIP_MEMORY_SCOPE_AGENT);
            }
            __syncthreads();  // all 16 slice stores issued+complete (vmcnt drain)
            if (tid == 0) {
                __threadfence();  // release: slice visible before flag
                __hip_atomic_store(flags + par * NB + bid, t + 1,
                                   __ATOMIC_RELAXED, __HIP_MEMORY_SCOPE_AGENT);
            }
        }
    }
}

extern "C" void kernel_launch(void* const* d_in, const int* in_sizes, int n_in,
                              void* d_out, int out_size, void* d_ws, size_t ws_size,
                              hipStream_t stream) {
    const float* X      = (const float*)d_in[0];
    const float* state0 = (const float*)d_in[1];
    const float* W_in   = (const float*)d_in[2];
    const float* W_res  = (const float*)d_in[3];
    const float* W_out  = (const float*)d_in[4];
    float* out = (float*)d_out;

    float* stbuf = (float*)d_ws;                              // 2*4096*4 = 32 KiB
    int*   flags = (int*)((char*)d_ws + 2 * RES_N * sizeof(float));  // 2*256*4 = 2 KiB

    // Flags must start at 0 every call (ws is NOT re-poisoned between replays).
    hipMemsetAsync(flags, 0, 2 * NB * sizeof(int), stream);

    esn_persistent<<<dim3(NB), dim3(NT), 0, stream>>>(
        X, state0, W_in, W_res, W_out, out, stbuf, flags);
}

// Round 3
// 89224.707 us; speedup vs baseline: 3.5406x; 3.5406x over previous
//
#include <hip/hip_runtime.h>

#define T_STEPS  8192
#define INPUT_N  256
#define OUTPUT_N 256
#define RES_N    4096
#define NB       256   // blocks (1 per CU)
#define NT       1024  // threads per block (16 waves)
#define RPB      16    // W_res rows per block

// Persistent ESN kernel, register-resident W_res.
// Block bid owns rows [bid*16, bid*16+16) of W_res/W_in and row bid of W_out.
// Thread decomposition: rg = tid>>8 (4 row-groups of 4 rows), cg = tid&255.
// Each thread: 4 rows x 4 float4 state-chunks = 64 weight floats in VGPRs.
__global__ __launch_bounds__(NT, 2) void esn_persistent(
    const float* __restrict__ X,       // [T, 256]
    const float* __restrict__ state0,  // [4096]
    const float* __restrict__ W_in,    // [4096, 256]
    const float* __restrict__ W_res,   // [4096, 4096]
    const float* __restrict__ W_out,   // [256, 4096]
    float* __restrict__ out,           // [T, 256]
    float* __restrict__ stbuf,         // ws: [2][4096]
    int*   __restrict__ flags)         // ws: [2][256], zeroed per call
{
    const int tid  = threadIdx.x;
    const int bid  = blockIdx.x;
    const int wid  = tid >> 6;          // wave 0..15
    const int lane = tid & 63;
    const int rg   = tid >> 8;          // row-group 0..3 (rows rg*4..rg*4+3)
    const int wg   = (tid >> 6) & 3;    // wave within row-group
    const int cg   = tid & 255;         // state-chunk column group

    __shared__ float lds_s[RES_N];          // staged state_{t-1} (16 KB)
    __shared__ float lds_x[INPUT_N];        // staged x_t
    __shared__ float lds_part[4][4][4];     // [rg][wg][r] row partials
    __shared__ float lds_pp[16];            // per-wave pred partials

    // ---- one-time: persistent weights into registers (64+4+4 floats) ----
    float4 wres[4][4];
    float  win[4];
#pragma unroll
    for (int r = 0; r < 4; ++r) {
        const int grow = bid * RPB + rg * 4 + r;
        const float* wr = W_res + (size_t)grow * RES_N;
#pragma unroll
        for (int c = 0; c < 4; ++c)
            wres[r][c] = *(const float4*)(wr + 4 * (cg + 256 * c));
        win[r] = W_in[(size_t)grow * INPUT_N + cg];  // cg covers all 256 inputs
    }
    const float4 wout = *(const float4*)(W_out + (size_t)bid * RES_N + 4 * tid);

    // Iteration t: stage state_{t-1}; pred_{t-1} (t>0); state_t (t<T).
#pragma unroll 1
    for (int t = 0; t <= T_STEPS; ++t) {
        const int par  = t & 1;
        const int ppar = (t - 1) & 1;

        // ---- grid barrier: wait for all blocks' state_{t-1} ----
        if (t > 0) {
            if (tid < NB) {
                const int* f = flags + ppar * NB + tid;
                while (__hip_atomic_load(f, __ATOMIC_RELAXED,
                                         __HIP_MEMORY_SCOPE_AGENT) < t) { }
            }
        }
        __syncthreads();

        // ---- stage state_{t-1} and x_t into LDS ----
        const float* src = (t == 0) ? state0 : (stbuf + (size_t)ppar * RES_N);
#pragma unroll
        for (int j = 0; j < 4; ++j) {
            const float v = __hip_atomic_load(src + tid + NT * j, __ATOMIC_RELAXED,
                                              __HIP_MEMORY_SCOPE_AGENT);
            lds_s[tid + NT * j] = v;
        }
        if (t < T_STEPS && tid < INPUT_N)
            lds_x[tid] = X[(size_t)t * INPUT_N + tid];
        __syncthreads();

        // ---- pred_{t-1} partial: W_out[bid] . state_{t-1} ----
        if (t > 0) {
            const float4 s4 = *(const float4*)(lds_s + 4 * tid);
            float pp = wout.x * s4.x + wout.y * s4.y + wout.z * s4.z + wout.w * s4.w;
#pragma unroll
            for (int m = 32; m > 0; m >>= 1) pp += __shfl_xor(pp, m, 64);
            if (lane == 0) lds_pp[wid] = pp;
        }

        // ---- state_t partials: 4 rows x 4 float4 chunks per thread ----
        if (t < T_STEPS) {
            float p0 = 0.f, p1 = 0.f, p2 = 0.f, p3 = 0.f;
#pragma unroll
            for (int c = 0; c < 4; ++c) {
                const float4 s = *(const float4*)(lds_s + 4 * (cg + 256 * c));
                p0 += wres[0][c].x * s.x + wres[0][c].y * s.y
                    + wres[0][c].z * s.z + wres[0][c].w * s.w;
                p1 += wres[1][c].x * s.x + wres[1][c].y * s.y
                    + wres[1][c].z * s.z + wres[1][c].w * s.w;
                p2 += wres[2][c].x * s.x + wres[2][c].y * s.y
                    + wres[2][c].z * s.z + wres[2][c].w * s.w;
                p3 += wres[3][c].x * s.x + wres[3][c].y * s.y
                    + wres[3][c].z * s.z + wres[3][c].w * s.w;
            }
            const float xv = lds_x[cg];
            p0 += win[0] * xv;
            p1 += win[1] * xv;
            p2 += win[2] * xv;
            p3 += win[3] * xv;
#pragma unroll
            for (int m = 32; m > 0; m >>= 1) {
                p0 += __shfl_xor(p0, m, 64);
                p1 += __shfl_xor(p1, m, 64);
                p2 += __shfl_xor(p2, m, 64);
                p3 += __shfl_xor(p3, m, 64);
            }
            if (lane == 0) {
                lds_part[rg][wg][0] = p0;
                lds_part[rg][wg][1] = p1;
                lds_part[rg][wg][2] = p2;
                lds_part[rg][wg][3] = p3;
            }
        }
        __syncthreads();

        // ---- finals ----
        if (t > 0 && tid < 16) {
            float pv = lds_pp[tid];
#pragma unroll
            for (int m = 8; m > 0; m >>= 1) pv += __shfl_xor(pv, m, 64);
            if (tid == 0) out[(size_t)(t - 1) * OUTPUT_N + bid] = pv;
        }
        if (t < T_STEPS) {
            if (tid < RPB) {
                const int lrg = tid >> 2, lr = tid & 3;
                const float v = lds_part[lrg][0][lr] + lds_part[lrg][1][lr]
                              + lds_part[lrg][2][lr] + lds_part[lrg][3][lr];
                const float ns = tanhf(v);
                __hip_atomic_store(stbuf + (size_t)par * RES_N + bid * RPB + tid,
                                   ns, __ATOMIC_RELAXED, __HIP_MEMORY_SCOPE_AGENT);
            }
            __syncthreads();  // drains each thread's stores (vmcnt 0) before flag
            if (tid == 0) {
                __threadfence();  // device-scope release: slice visible before flag
                __hip_atomic_store(flags + par * NB + bid, t + 1,
                                   __ATOMIC_RELAXED, __HIP_MEMORY_SCOPE_AGENT);
            }
        }
    }
}

extern "C" void kernel_launch(void* const* d_in, const int* in_sizes, int n_in,
                              void* d_out, int out_size, void* d_ws, size_t ws_size,
                              hipStream_t stream) {
    const float* X      = (const float*)d_in[0];
    const float* state0 = (const float*)d_in[1];
    const float* W_in   = (const float*)d_in[2];
    const float* W_res  = (const float*)d_in[3];
    const float* W_out  = (const float*)d_in[4];
    float* out = (float*)d_out;

    float* stbuf = (float*)d_ws;                                     // 32 KiB
    int*   flags = (int*)((char*)d_ws + 2 * RES_N * sizeof(float));  // 2 KiB

    // Flags must start at 0 every call (ws is NOT re-poisoned between replays).
    (void)hipMemsetAsync(flags, 0, 2 * NB * sizeof(int), stream);

    esn_persistent<<<dim3(NB), dim3(NT), 0, stream>>>(
        X, state0, W_in, W_res, W_out, out, stbuf, flags);
}

// Round 4
// 88629.559 us; speedup vs baseline: 3.5643x; 1.0067x over previous
//
#include <hip/hip_runtime.h>

#define T_STEPS  8192
#define INPUT_N  256
#define OUTPUT_N 256
#define RES_N    4096
#define NB       256   // blocks (1 per CU)
#define NT       1024  // threads per block (16 waves)
#define RPB      16    // W_res rows per block

// Pin a value into a VGPR: the asm result is not rematerializable, so the
// backend can neither sink the feeding load into the loop nor "spill" it by
// re-loading from global. This is what keeps W_res register-resident.
#define PIN(x)  asm volatile("" : "+v"(x))
#define PIN4(v) do { PIN((v).x); PIN((v).y); PIN((v).z); PIN((v).w); } while (0)

// Persistent ESN kernel, register-resident W_res.
// Block bid owns rows [bid*16, bid*16+16) of W_res/W_in and row bid of W_out.
// Thread decomposition: rg = tid>>8 (4 row-groups of 4 rows), cg = tid&255.
// Each thread: 4 rows x 4 float4 state-chunks = 64 weight floats in VGPRs.
__global__ __launch_bounds__(NT, 2) void esn_persistent(
    const float* __restrict__ X,       // [T, 256]
    const float* __restrict__ state0,  // [4096]
    const float* __restrict__ W_in,    // [4096, 256]
    const float* __restrict__ W_res,   // [4096, 4096]
    const float* __restrict__ W_out,   // [256, 4096]
    float* __restrict__ out,           // [T, 256]
    float* __restrict__ stbuf,         // ws: [2][4096]
    int*   __restrict__ flags)         // ws: [2][256], zeroed per call
{
    const int tid  = threadIdx.x;
    const int bid  = blockIdx.x;
    const int wid  = tid >> 6;          // wave 0..15
    const int lane = tid & 63;
    const int rg   = tid >> 8;          // row-group 0..3 (rows rg*4..rg*4+3)
    const int wg   = (tid >> 6) & 3;    // wave within row-group
    const int cg   = tid & 255;         // state-chunk column group

    __shared__ float lds_s[RES_N];          // staged state_{t-1} (16 KB)
    __shared__ float lds_x[INPUT_N];        // staged x_t
    __shared__ float lds_part[4][4][4];     // [rg][wg][r] row partials
    __shared__ float lds_pp[16];            // per-wave pred partials

    // ---- one-time: persistent weights into registers (64+4+4 floats) ----
    float4 wres[4][4];
    float  win[4];
#pragma unroll
    for (int r = 0; r < 4; ++r) {
        const int grow = bid * RPB + rg * 4 + r;
        const float* wr = W_res + (size_t)grow * RES_N;
#pragma unroll
        for (int c = 0; c < 4; ++c)
            wres[r][c] = *(const float4*)(wr + 4 * (cg + 256 * c));
        win[r] = W_in[(size_t)grow * INPUT_N + cg];  // cg covers all 256 inputs
    }
    float4 wout = *(const float4*)(W_out + (size_t)bid * RES_N + 4 * tid);

    // Pin all persistent weights so they stay live in VGPRs across the loop.
#pragma unroll
    for (int r = 0; r < 4; ++r) {
#pragma unroll
        for (int c = 0; c < 4; ++c) PIN4(wres[r][c]);
        PIN(win[r]);
    }
    PIN4(wout);

    // Iteration t: stage state_{t-1}; pred_{t-1} (t>0); state_t (t<T).
#pragma unroll 1
    for (int t = 0; t <= T_STEPS; ++t) {
        const int par  = t & 1;
        const int ppar = (t - 1) & 1;

        // ---- grid barrier: wait for all blocks' state_{t-1} ----
        if (t > 0) {
            if (tid < NB) {
                const int* f = flags + ppar * NB + tid;
                while (__hip_atomic_load(f, __ATOMIC_RELAXED,
                                         __HIP_MEMORY_SCOPE_AGENT) < t) { }
            }
        }
        __syncthreads();

        // ---- stage state_{t-1} and x_t into LDS ----
        const float* src = (t == 0) ? state0 : (stbuf + (size_t)ppar * RES_N);
#pragma unroll
        for (int j = 0; j < 4; ++j) {
            const float v = __hip_atomic_load(src + tid + NT * j, __ATOMIC_RELAXED,
                                              __HIP_MEMORY_SCOPE_AGENT);
            lds_s[tid + NT * j] = v;
        }
        if (t < T_STEPS && tid < INPUT_N)
            lds_x[tid] = X[(size_t)t * INPUT_N + tid];
        __syncthreads();

        // ---- pred_{t-1} partial: W_out[bid] . state_{t-1} ----
        if (t > 0) {
            const float4 s4 = *(const float4*)(lds_s + 4 * tid);
            float pp = wout.x * s4.x + wout.y * s4.y + wout.z * s4.z + wout.w * s4.w;
#pragma unroll
            for (int m = 32; m > 0; m >>= 1) pp += __shfl_xor(pp, m, 64);
            if (lane == 0) lds_pp[wid] = pp;
        }

        // ---- state_t partials: 4 rows x 4 float4 chunks per thread ----
        if (t < T_STEPS) {
            float p0 = 0.f, p1 = 0.f, p2 = 0.f, p3 = 0.f;
#pragma unroll
            for (int c = 0; c < 4; ++c) {
                const float4 s = *(const float4*)(lds_s + 4 * (cg + 256 * c));
                p0 += wres[0][c].x * s.x + wres[0][c].y * s.y
                    + wres[0][c].z * s.z + wres[0][c].w * s.w;
                p1 += wres[1][c].x * s.x + wres[1][c].y * s.y
                    + wres[1][c].z * s.z + wres[1][c].w * s.w;
                p2 += wres[2][c].x * s.x + wres[2][c].y * s.y
                    + wres[2][c].z * s.z + wres[2][c].w * s.w;
                p3 += wres[3][c].x * s.x + wres[3][c].y * s.y
                    + wres[3][c].z * s.z + wres[3][c].w * s.w;
            }
            const float xv = lds_x[cg];
            p0 += win[0] * xv;
            p1 += win[1] * xv;
            p2 += win[2] * xv;
            p3 += win[3] * xv;
#pragma unroll
            for (int m = 32; m > 0; m >>= 1) {
                p0 += __shfl_xor(p0, m, 64);
                p1 += __shfl_xor(p1, m, 64);
                p2 += __shfl_xor(p2, m, 64);
                p3 += __shfl_xor(p3, m, 64);
            }
            if (lane == 0) {
                lds_part[rg][wg][0] = p0;
                lds_part[rg][wg][1] = p1;
                lds_part[rg][wg][2] = p2;
                lds_part[rg][wg][3] = p3;
            }
        }
        __syncthreads();

        // ---- finals ----
        if (t > 0 && tid < 16) {
            float pv = lds_pp[tid];
#pragma unroll
            for (int m = 8; m > 0; m >>= 1) pv += __shfl_xor(pv, m, 64);
            if (tid == 0) out[(size_t)(t - 1) * OUTPUT_N + bid] = pv;
        }
        if (t < T_STEPS) {
            if (tid < RPB) {
                const int lrg = tid >> 2, lr = tid & 3;
                const float v = lds_part[lrg][0][lr] + lds_part[lrg][1][lr]
                              + lds_part[lrg][2][lr] + lds_part[lrg][3][lr];
                const float ns = tanhf(v);
                __hip_atomic_store(stbuf + (size_t)par * RES_N + bid * RPB + tid,
                                   ns, __ATOMIC_RELAXED, __HIP_MEMORY_SCOPE_AGENT);
            }
            __syncthreads();  // drains each thread's stores (vmcnt 0) before flag
            if (tid == 0) {
                __threadfence();  // device-scope release: slice visible before flag
                __hip_atomic_store(flags + par * NB + bid, t + 1,
                                   __ATOMIC_RELAXED, __HIP_MEMORY_SCOPE_AGENT);
            }
        }
    }
}

extern "C" void kernel_launch(void* const* d_in, const int* in_sizes, int n_in,
                              void* d_out, int out_size, void* d_ws, size_t ws_size,
                              hipStream_t stream) {
    const float* X      = (const float*)d_in[0];
    const float* state0 = (const float*)d_in[1];
    const float* W_in   = (const float*)d_in[2];
    const float* W_res  = (const float*)d_in[3];
    const float* W_out  = (const float*)d_in[4];
    float* out = (float*)d_out;

    float* stbuf = (float*)d_ws;                                     // 32 KiB
    int*   flags = (int*)((char*)d_ws + 2 * RES_N * sizeof(float));  // 2 KiB

    // Flags must start at 0 every call (ws is NOT re-poisoned between replays).
    (void)hipMemsetAsync(flags, 0, 2 * NB * sizeof(int), stream);

    esn_persistent<<<dim3(NB), dim3(NT), 0, stream>>>(
        X, state0, W_in, W_res, W_out, out, stbuf, flags);
}